// Round 7
// baseline (15.501 us; speedup 1.0000x reference)
//
#include <hip/hip_runtime.h>
#include <hip/hip_bf16.h>

#define LOOKBACK 8
#define HID 32
#define TB 256                 // threads per block == t's per block
#define NR  (TB + LOOKBACK)    // 264 K rows per block
#define RST 20                 // uints per K row (16 used + 4 pad) = 80B stride
#define EPS 1e-6f

// sP (LDS) param layout (floats)
#define WS_AQ  0     // [4][32]
#define WS_CQ  128   // [32]
#define WS_AK  160   // [4][32]
#define WS_CK  288   // [32]
#define WS_AVW 320   // [4]
#define WS_CVW 324   // scalar
#define WS_N   336

__device__ __forceinline__ float phi1(float z) {
    return (z >= 0.0f ? z : 0.01f * z) + 1.0f;
}
__device__ __forceinline__ unsigned pack_bf16(float a, float b) {
    __hip_bfloat162 h = __float22bfloat162_rn(make_float2(a, b));
    return *reinterpret_cast<unsigned*>(&h);
}
__device__ __forceinline__ float blo(unsigned u) {   // packed-first elem (ch 2m)
    return __uint_as_float(u << 16);
}
__device__ __forceinline__ float bhi(unsigned u) {   // ch 2m+1
    return __uint_as_float(u & 0xffff0000u);
}

__global__ __launch_bounds__(TB) void ga_fused(
    const float* __restrict__ x,            // (B, L, 4)
    const float* __restrict__ sbp, const float* __restrict__ vsp,
    const float* __restrict__ vbp, const float* __restrict__ bwp,
    const float* __restrict__ WQ,  const float* __restrict__ WK,
    const float* __restrict__ WV,  const float* __restrict__ wh,
    const float* __restrict__ bhp,
    float* __restrict__ out,                // pred (B*T) then weights (B*T*8)
    int B, int L)
{
    const int T   = L - LOOKBACK;
    const int bb  = blockIdx.y;
    const int t0  = blockIdx.x * TB;
    const int tid = threadIdx.x;

    __shared__ float    sP[WS_N];
    __shared__ unsigned sK[NR * RST];       // bf16-packed K rows
    __shared__ float    sVW[NR];

    const float* xb = x + (size_t)bb * L * 4;

    // ---- prefetch this thread's query x (hides under collapse + phase A) ----
    const int t = t0 + tid;
    const bool valid = (t < T);
    const float4 xq = *reinterpret_cast<const float4*>(
        xb + (size_t)(valid ? t + LOOKBACK : 0) * 4);

    // ---- Phase 0: in-block parameter collapse (threads 0..95) ----
    if (tid < 96) {
        const int h   = tid & 31;
        const int mat = tid >> 5;          // 0=Q, 1=K, 2=V
        const float* W = (mat == 0) ? WQ : (mat == 1) ? WK : WV;
        float w[11];
#pragma unroll 1
        for (int j = 0; j < 11; ++j) w[j] = W[j * HID + h];

        const float b0 = bwp[0], b1 = bwp[1], b2 = bwp[2];
        const float b3 = bwp[3], b4 = bwp[4], b5 = bwp[5];
        const float v0 = vsp[0], v1 = vsp[1], v2 = vsp[2], v3 = vsp[3];
        const float u0 = vbp[0], u1 = vbp[1], u2 = vbp[2], u3 = vbp[3];
        const float s0 = 1.0f + sbp[0];

        // x_d coefficients. BIV_I=[0,0,0,1,1,2], BIV_J=[1,2,3,2,3,3]
        const float a0 = v0*w[1] + b0*w[5] + b1*w[6] + b2*w[7];
        const float a1 = v1*w[2] - b0*w[5] + b3*w[8] + b4*w[9];
        const float a2 = v2*w[3] - b1*w[6] - b3*w[8] + b5*w[10];
        const float a3 = v3*w[4] - b2*w[7] - b4*w[9] - b5*w[10];
        const float c  = s0*w[0] + u0*w[1] + u1*w[2] + u2*w[3] + u3*w[4];

        if (mat == 0) {
            sP[WS_AQ + 0*HID + h] = a0; sP[WS_AQ + 1*HID + h] = a1;
            sP[WS_AQ + 2*HID + h] = a2; sP[WS_AQ + 3*HID + h] = a3;
            sP[WS_CQ + h] = c;
        } else if (mat == 1) {
            sP[WS_AK + 0*HID + h] = a0; sP[WS_AK + 1*HID + h] = a1;
            sP[WS_AK + 2*HID + h] = a2; sP[WS_AK + 3*HID + h] = a3;
            sP[WS_CK + h] = c;
        } else {
            const float ww = wh[h];
            float r[5] = { a0*ww, a1*ww, a2*ww, a3*ww, c*ww };
#pragma unroll
            for (int off = 16; off > 0; off >>= 1) {
#pragma unroll
                for (int i = 0; i < 5; ++i) r[i] += __shfl_down(r[i], off, 32);
            }
            if (h == 0) {
                sP[WS_AVW + 0] = r[0]; sP[WS_AVW + 1] = r[1];
                sP[WS_AVW + 2] = r[2]; sP[WS_AVW + 3] = r[3];
                sP[WS_CVW]     = r[4];
            }
        }
    }
    __syncthreads();

    // ---- Phase A: bf16 K rows + V.w_head (rolled octet loop) ----
    const float avw0 = sP[WS_AVW + 0], avw1 = sP[WS_AVW + 1];
    const float avw2 = sP[WS_AVW + 2], avw3 = sP[WS_AVW + 3];
    const float cvw  = sP[WS_CVW];

    const int npos = min(NR, L - t0);
#pragma unroll 1
    for (int r = tid; r < npos; r += TB) {
        const float4 xv = *reinterpret_cast<const float4*>(xb + (size_t)(t0 + r) * 4);

        sVW[r] = cvw + xv.x*avw0 + xv.y*avw1 + xv.z*avw2 + xv.w*avw3;

        unsigned* dst = &sK[r * RST];
#pragma unroll 1
        for (int oc = 0; oc < 4; ++oc) {
            const int hb = oc * 8;
            const float4 c0 = *reinterpret_cast<const float4*>(&sP[WS_CK + hb]);
            const float4 c1 = *reinterpret_cast<const float4*>(&sP[WS_CK + hb + 4]);
            const float4 a0l = *reinterpret_cast<const float4*>(&sP[WS_AK + 0*HID + hb]);
            const float4 a0h = *reinterpret_cast<const float4*>(&sP[WS_AK + 0*HID + hb + 4]);
            const float4 a1l = *reinterpret_cast<const float4*>(&sP[WS_AK + 1*HID + hb]);
            const float4 a1h = *reinterpret_cast<const float4*>(&sP[WS_AK + 1*HID + hb + 4]);
            const float4 a2l = *reinterpret_cast<const float4*>(&sP[WS_AK + 2*HID + hb]);
            const float4 a2h = *reinterpret_cast<const float4*>(&sP[WS_AK + 2*HID + hb + 4]);
            const float4 a3l = *reinterpret_cast<const float4*>(&sP[WS_AK + 3*HID + hb]);
            const float4 a3h = *reinterpret_cast<const float4*>(&sP[WS_AK + 3*HID + hb + 4]);

            const float z0 = phi1(c0.x + xv.x*a0l.x + xv.y*a1l.x + xv.z*a2l.x + xv.w*a3l.x);
            const float z1 = phi1(c0.y + xv.x*a0l.y + xv.y*a1l.y + xv.z*a2l.y + xv.w*a3l.y);
            const float z2 = phi1(c0.z + xv.x*a0l.z + xv.y*a1l.z + xv.z*a2l.z + xv.w*a3l.z);
            const float z3 = phi1(c0.w + xv.x*a0l.w + xv.y*a1l.w + xv.z*a2l.w + xv.w*a3l.w);
            const float z4 = phi1(c1.x + xv.x*a0h.x + xv.y*a1h.x + xv.z*a2h.x + xv.w*a3h.x);
            const float z5 = phi1(c1.y + xv.x*a0h.y + xv.y*a1h.y + xv.z*a2h.y + xv.w*a3h.y);
            const float z6 = phi1(c1.z + xv.x*a0h.z + xv.y*a1h.z + xv.z*a2h.z + xv.w*a3h.z);
            const float z7 = phi1(c1.w + xv.x*a0h.w + xv.y*a1h.w + xv.z*a2h.w + xv.w*a3h.w);

            *reinterpret_cast<uint4*>(dst + oc*4) = make_uint4(
                pack_bf16(z0, z1), pack_bf16(z2, z3),
                pack_bf16(z4, z5), pack_bf16(z6, z7));
        }
    }
    __syncthreads();

    // ---- Phase B: rolled octet loop; q-slice + 8 window partial dots ----
    if (!valid) return;

    float sc[LOOKBACK];
#pragma unroll
    for (int l = 0; l < LOOKBACK; ++l) sc[l] = 0.0f;

#pragma unroll 1
    for (int oc = 0; oc < 4; ++oc) {
        const int hb = oc * 8;
        const float4 c0 = *reinterpret_cast<const float4*>(&sP[WS_CQ + hb]);
        const float4 c1 = *reinterpret_cast<const float4*>(&sP[WS_CQ + hb + 4]);
        const float4 a0l = *reinterpret_cast<const float4*>(&sP[WS_AQ + 0*HID + hb]);
        const float4 a0h = *reinterpret_cast<const float4*>(&sP[WS_AQ + 0*HID + hb + 4]);
        const float4 a1l = *reinterpret_cast<const float4*>(&sP[WS_AQ + 1*HID + hb]);
        const float4 a1h = *reinterpret_cast<const float4*>(&sP[WS_AQ + 1*HID + hb + 4]);
        const float4 a2l = *reinterpret_cast<const float4*>(&sP[WS_AQ + 2*HID + hb]);
        const float4 a2h = *reinterpret_cast<const float4*>(&sP[WS_AQ + 2*HID + hb + 4]);
        const float4 a3l = *reinterpret_cast<const float4*>(&sP[WS_AQ + 3*HID + hb]);
        const float4 a3h = *reinterpret_cast<const float4*>(&sP[WS_AQ + 3*HID + hb + 4]);

        const float q0 = phi1(c0.x + xq.x*a0l.x + xq.y*a1l.x + xq.z*a2l.x + xq.w*a3l.x);
        const float q1 = phi1(c0.y + xq.x*a0l.y + xq.y*a1l.y + xq.z*a2l.y + xq.w*a3l.y);
        const float q2 = phi1(c0.z + xq.x*a0l.z + xq.y*a1l.z + xq.z*a2l.z + xq.w*a3l.z);
        const float q3 = phi1(c0.w + xq.x*a0l.w + xq.y*a1l.w + xq.z*a2l.w + xq.w*a3l.w);
        const float q4 = phi1(c1.x + xq.x*a0h.x + xq.y*a1h.x + xq.z*a2h.x + xq.w*a3h.x);
        const float q5 = phi1(c1.y + xq.x*a0h.y + xq.y*a1h.y + xq.z*a2h.y + xq.w*a3h.y);
        const float q6 = phi1(c1.z + xq.x*a0h.z + xq.y*a1h.z + xq.z*a2h.z + xq.w*a3h.z);
        const float q7 = phi1(c1.w + xq.x*a0h.w + xq.y*a1h.w + xq.z*a2h.w + xq.w*a3h.w);

#pragma unroll
        for (int l = 0; l < LOOKBACK; ++l) {
            const uint4 w = *reinterpret_cast<const uint4*>(
                &sK[(tid + l) * RST + oc * 4]);
            sc[l] += blo(w.x)*q0 + bhi(w.x)*q1
                   + blo(w.y)*q2 + bhi(w.y)*q3
                   + blo(w.z)*q4 + bhi(w.z)*q5
                   + blo(w.w)*q6 + bhi(w.w)*q7;
        }
    }

    float ssum = 0.0f, p = 0.0f;
#pragma unroll
    for (int l = 0; l < LOOKBACK; ++l) {
        ssum += sc[l];
        p    += sc[l] * sVW[tid + l];
    }
    const float inv = 1.0f / (ssum + EPS);

    out[(size_t)bb * T + t] = p * inv + bhp[0];

    float* wout = out + (size_t)B * T + ((size_t)bb * T + t) * LOOKBACK;
    *reinterpret_cast<float4*>(wout) =
        make_float4(sc[0]*inv, sc[1]*inv, sc[2]*inv, sc[3]*inv);
    *reinterpret_cast<float4*>(wout + 4) =
        make_float4(sc[4]*inv, sc[5]*inv, sc[6]*inv, sc[7]*inv);
}

extern "C" void kernel_launch(void* const* d_in, const int* in_sizes, int n_in,
                              void* d_out, int out_size, void* d_ws, size_t ws_size,
                              hipStream_t stream) {
    const float* x  = (const float*)d_in[0];
    const float* sb = (const float*)d_in[1];
    const float* vs = (const float*)d_in[2];
    const float* vb = (const float*)d_in[3];
    const float* bw = (const float*)d_in[4];
    const float* WQ = (const float*)d_in[5];
    const float* WK = (const float*)d_in[6];
    const float* WV = (const float*)d_in[7];
    const float* wh = (const float*)d_in[8];
    const float* bh = (const float*)d_in[9];
    float* out = (float*)d_out;

    // in_sizes[0] = B*L*4 ; out_size = B*(L-LOOKBACK)*(1+LOOKBACK)
    const long long bl = (long long)in_sizes[0] / 4;            // B*L
    const long long bt = (long long)out_size / (1 + LOOKBACK);  // B*(L-8)
    const int B = (int)((bl - bt) / LOOKBACK);
    const int L = (int)(bl / B);
    const int T = L - LOOKBACK;

    dim3 grid((T + TB - 1) / TB, B);
    ga_fused<<<grid, TB, 0, stream>>>(x, sb, vs, vb, bw, WQ, WK, WV, wh, bh,
                                      out, B, L);
}